// Round 5
// baseline (667.701 us; speedup 1.0000x reference)
//
#include <hip/hip_runtime.h>

// ---------------------------------------------------------------------------
// SelfAttention (B=2,S=2048,D=4096, NH=32,NKV=8,HD=128, NREP=4, non-causal)
// RoPE on K and V (reference quirk), NOT on Q.
// Round 5: round-4 structure (chunk-major conflict-free LDS, 4 blocks/CU,
//   setprio) with the v_cvt_pk_bf16_f32 asm REVERTED to proven f2b RNE
//   (round-3 numerics). If this fails, revert attn wholesale to round 3.
// ---------------------------------------------------------------------------

typedef short bf16x8 __attribute__((ext_vector_type(8)));
typedef float f32x4 __attribute__((ext_vector_type(4)));

__device__ __forceinline__ void load16(const void* g, void* l) {
  __builtin_amdgcn_global_load_lds(
      (const __attribute__((address_space(1))) void*)g,
      (__attribute__((address_space(3))) void*)l, 16, 0, 0);
}

__device__ __forceinline__ f32x4 mfma16(bf16x8 a, bf16x8 b, f32x4 c) {
  return __builtin_amdgcn_mfma_f32_16x16x32_bf16(a, b, c, 0, 0, 0);
}

__device__ __forceinline__ unsigned short f2b(float f) {
  union { float f; unsigned int u; } v; v.f = f;
  unsigned int u = v.u;
  return (unsigned short)((u + 0x7fffu + ((u >> 16) & 1u)) >> 16);
}
__device__ __forceinline__ float b2f(unsigned short u) {
  union { unsigned int u; float f; } v; v.u = ((unsigned int)u) << 16;
  return v.f;
}

// softmax scale folded with log2(e) so attention uses exp2 directly
#define QSCALE (0.08838834764831845f * 1.4426950408889634f)

// ---------------------------------------------------------------------------
__global__ __launch_bounds__(256) void cvt_f32_bf16(
    const float* __restrict__ in, unsigned short* __restrict__ out, int n4) {
  int idx = blockIdx.x * 256 + threadIdx.x;
  int stride = gridDim.x * 256;
  for (int i = idx; i < n4; i += stride) {
    float4 v = reinterpret_cast<const float4*>(in)[i];
    ushort4 o;
    o.x = f2b(v.x); o.y = f2b(v.y); o.z = f2b(v.z); o.w = f2b(v.w);
    reinterpret_cast<ushort4*>(out)[i] = o;
  }
}

// ---------------------------------------------------------------------------
// 256x256 tile, BK=32, 8 waves (2Mx4N), per-wave 128x64 output.
template <typename OutT, bool SCALEQ>
__global__ __launch_bounds__(512, 2) void gemm256(
    const unsigned short* __restrict__ A, const unsigned short* __restrict__ Bw,
    OutT* __restrict__ C, int M, int N, int K) {
  extern __shared__ char smem[];  // 131072 bytes
  const int tid = threadIdx.x;
  const int lane = tid & 63;
  const int w = tid >> 6;
  const int lr = lane & 15, lg = lane >> 4;
  const int wr = w >> 2, wc = w & 3;

  const int nbn = N >> 8;
  const int bid = blockIdx.x, nwg = gridDim.x;
  const int swz = (bid & 7) * (nwg >> 3) + (bid >> 3);  // nwg % 8 == 0
  const int bm = swz / nbn, bn = swz % nbn;

  const unsigned short* Ab = A + (size_t)bm * 256 * K;
  const unsigned short* Bb = Bw + (size_t)bn * 256 * K;

  int mS[2], kS[2];
#pragma unroll
  for (int r = 0; r < 2; ++r) {
    int L = r * 8192 + tid * 16;
    int U = L ^ (((L >> 9) & 1) << 5);
    mS[r] = U >> 6;
    kS[r] = (U & 63) >> 1;
  }
  const int wavebase = (tid & ~63) * 16;

  f32x4 acc[8][4];
#pragma unroll
  for (int m = 0; m < 8; ++m)
#pragma unroll
    for (int n = 0; n < 4; ++n) acc[m][n] = (f32x4){0.f, 0.f, 0.f, 0.f};

#define STAGE_A(tt)                                                          \
  {                                                                          \
    char* dst = smem + ((tt)&3) * 32768;                                     \
    _Pragma("unroll") for (int r = 0; r < 2; ++r)                            \
        load16(Ab + (size_t)mS[r] * K + (tt)*32 + kS[r],                     \
               dst + r * 8192 + wavebase);                                   \
  }
#define STAGE_B(tt)                                                          \
  {                                                                          \
    char* dst = smem + ((tt)&3) * 32768 + 16384;                             \
    _Pragma("unroll") for (int r = 0; r < 2; ++r)                            \
        load16(Bb + (size_t)mS[r] * K + (tt)*32 + kS[r],                     \
               dst + r * 8192 + wavebase);                                   \
  }

  for (int tt = 0; tt < 3; ++tt) { STAGE_A(tt); STAGE_B(tt); }

  const int NT = K >> 5;
  const int xorb = ((lr >> 3) & 1) << 5;
  const int aRowBase = (wr * 128 + lr) * 64 + lg * 16;
  const int bRowBase = (wc * 64 + lr) * 64 + lg * 16;

  for (int t = 0; t < NT; ++t) {
    const int rem = NT - 1 - t;
    if (rem >= 2)      asm volatile("s_waitcnt vmcnt(8)" ::: "memory");
    else if (rem == 1) asm volatile("s_waitcnt vmcnt(4)" ::: "memory");
    else               asm volatile("s_waitcnt vmcnt(0)" ::: "memory");
    __builtin_amdgcn_s_barrier();

    const char* buf = smem + (t & 3) * 32768;
    bf16x8 a0[4], b0[4];
#pragma unroll
    for (int mf = 0; mf < 4; ++mf)
      a0[mf] = *(const bf16x8*)(buf + ((aRowBase + mf * 16 * 64) ^ xorb));
#pragma unroll
    for (int nf = 0; nf < 4; ++nf)
      b0[nf] = *(const bf16x8*)(buf + 16384 + ((bRowBase + nf * 16 * 64) ^ xorb));
    if (t + 3 < NT) STAGE_A(t + 3);
    __builtin_amdgcn_s_barrier();
    asm volatile("s_waitcnt lgkmcnt(0)" ::: "memory");
    __builtin_amdgcn_sched_barrier(0);
    __builtin_amdgcn_s_setprio(1);
#pragma unroll
    for (int mf = 0; mf < 4; ++mf)
#pragma unroll
      for (int nf = 0; nf < 4; ++nf)
        acc[mf][nf] = mfma16(a0[mf], b0[nf], acc[mf][nf]);
    __builtin_amdgcn_s_setprio(0);
    __builtin_amdgcn_s_barrier();
    bf16x8 a1[4];
#pragma unroll
    for (int mf = 0; mf < 4; ++mf)
      a1[mf] = *(const bf16x8*)(buf + ((aRowBase + (4 + mf) * 16 * 64) ^ xorb));
    if (t + 3 < NT) STAGE_B(t + 3);
    __builtin_amdgcn_s_barrier();
    asm volatile("s_waitcnt lgkmcnt(0)" ::: "memory");
    __builtin_amdgcn_sched_barrier(0);
    __builtin_amdgcn_s_setprio(1);
#pragma unroll
    for (int mf = 0; mf < 4; ++mf)
#pragma unroll
      for (int nf = 0; nf < 4; ++nf)
        acc[4 + mf][nf] = mfma16(a1[mf], b0[nf], acc[4 + mf][nf]);
    __builtin_amdgcn_s_setprio(0);
  }
#undef STAGE_A
#undef STAGE_B

#pragma unroll
  for (int mf = 0; mf < 8; ++mf)
#pragma unroll
    for (int nf = 0; nf < 4; ++nf)
#pragma unroll
      for (int r = 0; r < 4; ++r) {
        int rowc = bm * 256 + wr * 128 + mf * 16 + lg * 4 + r;
        int colc = bn * 256 + wc * 64 + nf * 16 + lr;
        float v = acc[mf][nf][r];
        if constexpr (SCALEQ) v *= QSCALE;
        if constexpr (sizeof(OutT) == 2)
          C[(size_t)rowc * N + colc] = (OutT)f2b(v);
        else
          C[(size_t)rowc * N + colc] = v;
      }
}

// ---------------------------------------------------------------------------
// 128x128 tile GEMM — used for fused K/V projection.
template <typename OutT>
__global__ __launch_bounds__(256) void gemm_bt(
    const unsigned short* __restrict__ A, const unsigned short* __restrict__ Bw,
    OutT* __restrict__ C, int M, int N, int K) {
  alignas(16) __shared__ unsigned short As[4][128][8];
  alignas(16) __shared__ unsigned short Bs[4][128][8];
  const int t = threadIdx.x;
  const int lane = t & 63, w = t >> 6;
  const int lr = lane & 15, lg = lane >> 4;
  const int wr = w >> 1, wc = w & 1;

  const int nbn = N >> 7;
  const int nwg = gridDim.x;
  const int bid = blockIdx.x;
  const int swz = (bid & 7) * (nwg >> 3) + (bid >> 3);
  const int bm = swz / nbn, bn = swz % nbn;

  f32x4 acc[4][4];
#pragma unroll
  for (int m = 0; m < 4; ++m)
#pragma unroll
    for (int n = 0; n < 4; ++n) acc[m][n] = (f32x4){0.f, 0.f, 0.f, 0.f};

  const int c0 = t, c1 = 256 + t;
  const int kc0 = c0 >> 7, row0 = c0 & 127;
  const int kc1 = c1 >> 7, row1 = c1 & 127;
  const unsigned short* Ab = A + (size_t)(bm * 128) * K;
  const unsigned short* Bb = Bw + (size_t)(bn * 128) * K;
  char* AsB = (char*)&As[0][0][0];
  char* BsB = (char*)&Bs[0][0][0];
  const int ub0 = (t & 192) * 16;
  const int ub1 = (256 + (t & 192)) * 16;

  for (int k0 = 0; k0 < K; k0 += 32) {
    load16(Ab + (size_t)row0 * K + k0 + kc0 * 8, AsB + ub0);
    load16(Ab + (size_t)row1 * K + k0 + kc1 * 8, AsB + ub1);
    load16(Bb + (size_t)row0 * K + k0 + kc0 * 8, BsB + ub0);
    load16(Bb + (size_t)row1 * K + k0 + kc1 * 8, BsB + ub1);
    __syncthreads();
    bf16x8 af[4], bfr[4];
#pragma unroll
    for (int i = 0; i < 4; ++i)
      af[i] = *(const bf16x8*)&As[lg][wr * 64 + i * 16 + lr][0];
#pragma unroll
    for (int i = 0; i < 4; ++i)
      bfr[i] = *(const bf16x8*)&Bs[lg][wc * 64 + i * 16 + lr][0];
#pragma unroll
    for (int m = 0; m < 4; ++m)
#pragma unroll
      for (int n = 0; n < 4; ++n)
        acc[m][n] = mfma16(af[m], bfr[n], acc[m][n]);
    __syncthreads();
  }

#pragma unroll
  for (int m = 0; m < 4; ++m)
#pragma unroll
    for (int n = 0; n < 4; ++n)
#pragma unroll
      for (int r = 0; r < 4; ++r) {
        int rowc = bm * 128 + wr * 64 + m * 16 + lg * 4 + r;
        int colc = bn * 128 + wc * 64 + n * 16 + lr;
        float v = acc[m][n][r];
        if constexpr (sizeof(OutT) == 2)
          C[(size_t)rowc * N + colc] = (OutT)f2b(v);
        else
          C[(size_t)rowc * N + colc] = v;
      }
}

// ---------------------------------------------------------------------------
// RoPE on K and V from fused XKV (row stride 2048: cols [0,1024)=K, [1024,2048)=V).
__global__ __launch_bounds__(256) void rope_kv(
    const unsigned short* __restrict__ XKV,
    const float* __restrict__ fc, const float* __restrict__ fs,
    unsigned short* __restrict__ Kr, unsigned short* __restrict__ Vt) {
  __shared__ unsigned short Vl[128][66];
  const int t = threadIdx.x;
  const int bid = blockIdx.x;  // bkv*32 + stile
  const int stile = bid & 31, bkv = bid >> 5;
  const int b = bkv >> 3, kvh = bkv & 7;
  const int s0 = stile * 64;
  const int l = t & 63;
  const int jrow = t >> 6;

  for (int j = 0; j < 16; ++j) {
    int s = s0 + j * 4 + jrow;
    ushort2 v = *(const ushort2*)(XKV + (size_t)(b * 2048 + s) * 2048 + kvh * 128 + 2 * l);
    float c = fc[s * 64 + l], sn = fs[s * 64 + l];
    float xr = b2f(v.x), xi = b2f(v.y);
    ushort2 o;
    o.x = f2b(xr * c - xi * sn);
    o.y = f2b(xr * sn + xi * c);
    *(ushort2*)(Kr + ((size_t)bkv * 2048 + s) * 128 + 2 * l) = o;
  }
  for (int j = 0; j < 16; ++j) {
    int ss = j * 4 + jrow;
    int s = s0 + ss;
    ushort2 v = *(const ushort2*)(XKV + (size_t)(b * 2048 + s) * 2048 + 1024 + kvh * 128 + 2 * l);
    float c = fc[s * 64 + l], sn = fs[s * 64 + l];
    float xr = b2f(v.x), xi = b2f(v.y);
    Vl[2 * l][ss] = f2b(xr * c - xi * sn);
    Vl[2 * l + 1][ss] = f2b(xr * sn + xi * c);
  }
  __syncthreads();
  const int d = t >> 1, half = t & 1;
  unsigned short* vdst = Vt + ((size_t)bkv * 128 + d) * 2048 + s0 + half * 32;
#pragma unroll
  for (int e = 0; e < 32; e += 4) {
    ushort4 pk;
    pk.x = Vl[d][half * 32 + e];
    pk.y = Vl[d][half * 32 + e + 1];
    pk.z = Vl[d][half * 32 + e + 2];
    pk.w = Vl[d][half * 32 + e + 3];
    *(ushort4*)(vdst + e) = pk;
  }
}

// ---------------------------------------------------------------------------
// Flash attention, round 5 (= round-4 layouts, round-3 numerics).
// Grid 1024 = bh(64) x qtile(16); block 4 waves, wave owns 32 q-rows.
// KVBLK=32. Chunk-major LDS (all b128 reads land on 16B-slot == lr mod 8):
//   K: [16 dchunk][32 k][8]  (8KB x2)
//   V: [4 kchunk][128 d][8]  (8KB x2)
//   P: per-wave [4 kc][32 q][8] (2KB x4 waves), unpadded chunk-major.
// LDS total 40960B -> 4 blocks/CU. Max-free exp2 softmax, f2b (RNE) P->bf16.
__global__ __launch_bounds__(256, 4) void attn_fwd(
    const unsigned short* __restrict__ XQ, const unsigned short* __restrict__ Kr,
    const unsigned short* __restrict__ Vt, unsigned short* __restrict__ AO) {
  alignas(16) __shared__ char Ksm[2][8192];
  alignas(16) __shared__ char Vsm[2][8192];
  alignas(16) __shared__ unsigned short Ps[4][4][32][8];
  const int t = threadIdx.x;
  const int lane = t & 63, w = t >> 6;
  const int lr = lane & 15, lg = lane >> 4;

  const int bid = blockIdx.x;
  const int nwg = gridDim.x;  // 1024
  const int swz = (bid & 7) * (nwg >> 3) + (bid >> 3);
  const int qt = swz & 15;
  const int bh = swz >> 4;
  const int b = bh >> 5, h = bh & 31;
  const int bkv = b * 8 + (h >> 2);

  // Q fragments: 32 q-rows (2 x 16), full D=128 in regs
  bf16x8 qf[2][4];
#pragma unroll
  for (int q2 = 0; q2 < 2; ++q2) {
    const unsigned short* qp =
        XQ + ((size_t)(b * 2048 + qt * 128 + w * 32 + q2 * 16 + lr)) * 4096 +
        h * 128 + lg * 8;
#pragma unroll
    for (int dc = 0; dc < 4; ++dc) qf[q2][dc] = *(const bf16x8*)(qp + dc * 32);
  }

  f32x4 acc[2][8];
#pragma unroll
  for (int q2 = 0; q2 < 2; ++q2)
#pragma unroll
    for (int i = 0; i < 8; ++i) acc[q2][i] = (f32x4){0.f, 0.f, 0.f, 0.f};
  float l_[2][4] = {{0.f, 0.f, 0.f, 0.f}, {0.f, 0.f, 0.f, 0.f}};

  const unsigned short* Kbase = Kr + (size_t)bkv * 2048 * 128;
  const unsigned short* Vbase = Vt + (size_t)bkv * 128 * 2048;

  // staging: chunks c0 = t, c1 = t + 256 (512 x 16B per buffer)
  const int c0 = t, c1 = t + 256;
  const int kK0 = c0 & 31, dC0 = c0 >> 5;
  const int kK1 = c1 & 31, dC1 = c1 >> 5;
  const int vD0 = c0 & 127, vKc0 = c0 >> 7;
  const int vD1 = c1 & 127, vKc1 = c1 >> 7;
  const int dstb0 = (c0 & ~63) * 16;
  const int dstb1 = (c1 & ~63) * 16;

#define STAGE_KV(bufi, kt)                                                     \
  {                                                                            \
    load16(Kbase + (size_t)((kt)*32 + kK0) * 128 + dC0 * 8, Ksm[bufi] + dstb0);\
    load16(Kbase + (size_t)((kt)*32 + kK1) * 128 + dC1 * 8, Ksm[bufi] + dstb1);\
    load16(Vbase + (size_t)vD0 * 2048 + (kt)*32 + vKc0 * 8, Vsm[bufi] + dstb0);\
    load16(Vbase + (size_t)vD1 * 2048 + (kt)*32 + vKc1 * 8, Vsm[bufi] + dstb1);\
  }

  STAGE_KV(0, 0);
  asm volatile("s_waitcnt vmcnt(0)" ::: "memory");
  __builtin_amdgcn_s_barrier();

  unsigned short* Pw = &Ps[w][0][0][0];
  const int pbase = (lr >> 3) * 256 + (lr & 7);  // kc-part from lr, + e

  for (int kt = 0; kt < 64; ++kt) {
    const int cur = kt & 1;
    if (kt < 63) STAGE_KV(cur ^ 1, kt + 1);

    const char* Kc = Ksm[cur];
    const char* Vc = Vsm[cur];

    // QK^T + exp2 + P-store (per nf chunk of 16 k)
#pragma unroll
    for (int nf = 0; nf < 2; ++nf) {
      f32x4 s0 = (f32x4){0.f, 0.f, 0.f, 0.f};
      f32x4 s1 = (f32x4){0.f, 0.f, 0.f, 0.f};
      __builtin_amdgcn_s_setprio(1);
#pragma unroll
      for (int dc = 0; dc < 4; ++dc) {
        bf16x8 kf =
            *(const bf16x8*)(Kc + ((dc * 4 + lg) * 32 + nf * 16 + lr) * 16);
        s0 = mfma16(qf[0][dc], kf, s0);
        s1 = mfma16(qf[1][dc], kf, s1);
      }
      __builtin_amdgcn_s_setprio(0);
      const int pb = pbase + nf * 512;  // (nf*2)*256
#pragma unroll
      for (int r = 0; r < 4; ++r) {
        float p0 = __builtin_amdgcn_exp2f(s0[r]);
        float p1 = __builtin_amdgcn_exp2f(s1[r]);
        l_[0][r] += p0;
        l_[1][r] += p1;
        Pw[pb + (lg * 4 + r) * 8] = f2b(p0);
        Pw[pb + (16 + lg * 4 + r) * 8] = f2b(p1);
      }
    }

    // PV: A-frag = P[q=lr(+16)][k=lg*8..+7] (chunk lg), B-frag = V chunk lg
    bf16x8 pf0 = *(const bf16x8*)(Pw + (lg * 32 + lr) * 8);
    bf16x8 pf1 = *(const bf16x8*)(Pw + (lg * 32 + 16 + lr) * 8);
    __builtin_amdgcn_s_setprio(1);
#pragma unroll
    for (int dt = 0; dt < 8; ++dt) {
      bf16x8 vf = *(const bf16x8*)(Vc + (lg * 128 + dt * 16 + lr) * 16);
      acc[0][dt] = mfma16(pf0, vf, acc[0][dt]);
      acc[1][dt] = mfma16(pf1, vf, acc[1][dt]);
    }
    __builtin_amdgcn_s_setprio(0);

    asm volatile("s_waitcnt vmcnt(0)" ::: "memory");
    __builtin_amdgcn_s_barrier();
  }
#undef STAGE_KV

  // reduce l across the 16 lanes of each lg row-group
#pragma unroll
  for (int q2 = 0; q2 < 2; ++q2)
#pragma unroll
    for (int r = 0; r < 4; ++r) {
#pragma unroll
      for (int o = 1; o < 16; o <<= 1) l_[q2][r] += __shfl_xor(l_[q2][r], o);
    }

#pragma unroll
  for (int q2 = 0; q2 < 2; ++q2)
#pragma unroll
    for (int r = 0; r < 4; ++r) {
      float inv = 1.f / l_[q2][r];
      size_t rowb =
          ((size_t)(b * 2048 + qt * 128 + w * 32 + q2 * 16 + lg * 4 + r)) * 4096 +
          h * 128;
#pragma unroll
      for (int dt = 0; dt < 8; ++dt)
        AO[rowb + dt * 16 + lr] = f2b(acc[q2][dt][r] * inv);
    }
}

// ---------------------------------------------------------------------------
extern "C" void kernel_launch(void* const* d_in, const int* in_sizes, int n_in,
                              void* d_out, int out_size, void* d_ws, size_t ws_size,
                              hipStream_t stream) {
  const float* x  = (const float*)d_in[0];
  const float* fc = (const float*)d_in[2];
  const float* fs = (const float*)d_in[3];
  const float* wq = (const float*)d_in[4];
  const float* wk = (const float*)d_in[5];
  const float* wv = (const float*)d_in[6];
  const float* wo = (const float*)d_in[7];

  const size_t MB = 1024ull * 1024ull;
  char* ws = (char*)d_ws;
  unsigned short* Xb  = (unsigned short*)(ws);
  unsigned short* Wsc = (unsigned short*)(ws + 32 * MB);
  unsigned short* XKV = (unsigned short*)(ws + 64 * MB);  // 4096 x 2048 (16MB)
  unsigned short* Kr  = (unsigned short*)(ws);            // reuse Xb region
  unsigned short* Vt  = (unsigned short*)(ws + 8 * MB);
  unsigned short* AO  = (unsigned short*)(ws + 80 * MB);
  unsigned short* XQ  = (unsigned short*)d_out;

  (void)hipFuncSetAttribute((const void*)gemm256<unsigned short, true>,
                            hipFuncAttributeMaxDynamicSharedMemorySize, 131072);
  (void)hipFuncSetAttribute((const void*)gemm256<float, false>,
                            hipFuncAttributeMaxDynamicSharedMemorySize, 131072);

  dim3 blk(256);
  dim3 blk512(512);
  cvt_f32_bf16<<<2048, blk, 0, stream>>>(x, Xb, (2 * 2048 * 4096) / 4);
  cvt_f32_bf16<<<2048, blk, 0, stream>>>(wq, Wsc, (4096 * 4096) / 4);
  gemm256<unsigned short, true><<<256, blk512, 131072, stream>>>(
      Xb, Wsc, XQ, 4096, 4096, 4096);
  cvt_f32_bf16<<<2048, blk, 0, stream>>>(wk, Wsc, (1024 * 4096) / 4);
  cvt_f32_bf16<<<2048, blk, 0, stream>>>(wv, Wsc + 1024 * 4096, (1024 * 4096) / 4);
  gemm_bt<unsigned short><<<512, blk, 0, stream>>>(Xb, Wsc, XKV, 4096, 2048, 4096);
  rope_kv<<<512, blk, 0, stream>>>(XKV, fc, fs, Kr, Vt);
  attn_fwd<<<1024, blk, 0, stream>>>(XQ, Kr, Vt, AO);
  cvt_f32_bf16<<<2048, blk, 0, stream>>>(wo, Wsc, (4096 * 4096) / 4);
  gemm256<float, false><<<256, blk512, 131072, stream>>>(
      AO, Wsc, (float*)d_out, 4096, 4096, 4096);
}

// Round 6
// 618.909 us; speedup vs baseline: 1.0788x; 1.0788x over previous
//
#include <hip/hip_runtime.h>

// ---------------------------------------------------------------------------
// SelfAttention (B=2,S=2048,D=4096, NH=32,NKV=8,HD=128, NREP=4, non-causal)
// RoPE on K and V (reference quirk), NOT on Q.
// Round 6: attn KVBLK=64 (half the barrier/drain count vs r5), chunk-major
//   conflict-free LDS reads, 80KB LDS -> 2 blocks/CU (r3's proven occupancy,
//   avoids r5's L2 thrash), setprio removed from attn (m190: harms lockstep).
// ---------------------------------------------------------------------------

typedef short bf16x8 __attribute__((ext_vector_type(8)));
typedef float f32x4 __attribute__((ext_vector_type(4)));

__device__ __forceinline__ void load16(const void* g, void* l) {
  __builtin_amdgcn_global_load_lds(
      (const __attribute__((address_space(1))) void*)g,
      (__attribute__((address_space(3))) void*)l, 16, 0, 0);
}

__device__ __forceinline__ f32x4 mfma16(bf16x8 a, bf16x8 b, f32x4 c) {
  return __builtin_amdgcn_mfma_f32_16x16x32_bf16(a, b, c, 0, 0, 0);
}

__device__ __forceinline__ unsigned short f2b(float f) {
  union { float f; unsigned int u; } v; v.f = f;
  unsigned int u = v.u;
  return (unsigned short)((u + 0x7fffu + ((u >> 16) & 1u)) >> 16);
}
__device__ __forceinline__ float b2f(unsigned short u) {
  union { unsigned int u; float f; } v; v.u = ((unsigned int)u) << 16;
  return v.f;
}

// softmax scale folded with log2(e) so attention uses exp2 directly
#define QSCALE (0.08838834764831845f * 1.4426950408889634f)

// ---------------------------------------------------------------------------
__global__ __launch_bounds__(256) void cvt_f32_bf16(
    const float* __restrict__ in, unsigned short* __restrict__ out, int n4) {
  int idx = blockIdx.x * 256 + threadIdx.x;
  int stride = gridDim.x * 256;
  for (int i = idx; i < n4; i += stride) {
    float4 v = reinterpret_cast<const float4*>(in)[i];
    ushort4 o;
    o.x = f2b(v.x); o.y = f2b(v.y); o.z = f2b(v.z); o.w = f2b(v.w);
    reinterpret_cast<ushort4*>(out)[i] = o;
  }
}

// ---------------------------------------------------------------------------
// 256x256 tile, BK=32, 8 waves (2Mx4N), per-wave 128x64 output.
template <typename OutT, bool SCALEQ>
__global__ __launch_bounds__(512, 2) void gemm256(
    const unsigned short* __restrict__ A, const unsigned short* __restrict__ Bw,
    OutT* __restrict__ C, int M, int N, int K) {
  extern __shared__ char smem[];  // 131072 bytes
  const int tid = threadIdx.x;
  const int lane = tid & 63;
  const int w = tid >> 6;
  const int lr = lane & 15, lg = lane >> 4;
  const int wr = w >> 2, wc = w & 3;

  const int nbn = N >> 8;
  const int bid = blockIdx.x, nwg = gridDim.x;
  const int swz = (bid & 7) * (nwg >> 3) + (bid >> 3);  // nwg % 8 == 0
  const int bm = swz / nbn, bn = swz % nbn;

  const unsigned short* Ab = A + (size_t)bm * 256 * K;
  const unsigned short* Bb = Bw + (size_t)bn * 256 * K;

  int mS[2], kS[2];
#pragma unroll
  for (int r = 0; r < 2; ++r) {
    int L = r * 8192 + tid * 16;
    int U = L ^ (((L >> 9) & 1) << 5);
    mS[r] = U >> 6;
    kS[r] = (U & 63) >> 1;
  }
  const int wavebase = (tid & ~63) * 16;

  f32x4 acc[8][4];
#pragma unroll
  for (int m = 0; m < 8; ++m)
#pragma unroll
    for (int n = 0; n < 4; ++n) acc[m][n] = (f32x4){0.f, 0.f, 0.f, 0.f};

#define STAGE_A(tt)                                                          \
  {                                                                          \
    char* dst = smem + ((tt)&3) * 32768;                                     \
    _Pragma("unroll") for (int r = 0; r < 2; ++r)                            \
        load16(Ab + (size_t)mS[r] * K + (tt)*32 + kS[r],                     \
               dst + r * 8192 + wavebase);                                   \
  }
#define STAGE_B(tt)                                                          \
  {                                                                          \
    char* dst = smem + ((tt)&3) * 32768 + 16384;                             \
    _Pragma("unroll") for (int r = 0; r < 2; ++r)                            \
        load16(Bb + (size_t)mS[r] * K + (tt)*32 + kS[r],                     \
               dst + r * 8192 + wavebase);                                   \
  }

  for (int tt = 0; tt < 3; ++tt) { STAGE_A(tt); STAGE_B(tt); }

  const int NT = K >> 5;
  const int xorb = ((lr >> 3) & 1) << 5;
  const int aRowBase = (wr * 128 + lr) * 64 + lg * 16;
  const int bRowBase = (wc * 64 + lr) * 64 + lg * 16;

  for (int t = 0; t < NT; ++t) {
    const int rem = NT - 1 - t;
    if (rem >= 2)      asm volatile("s_waitcnt vmcnt(8)" ::: "memory");
    else if (rem == 1) asm volatile("s_waitcnt vmcnt(4)" ::: "memory");
    else               asm volatile("s_waitcnt vmcnt(0)" ::: "memory");
    __builtin_amdgcn_s_barrier();

    const char* buf = smem + (t & 3) * 32768;
    bf16x8 a0[4], b0[4];
#pragma unroll
    for (int mf = 0; mf < 4; ++mf)
      a0[mf] = *(const bf16x8*)(buf + ((aRowBase + mf * 16 * 64) ^ xorb));
#pragma unroll
    for (int nf = 0; nf < 4; ++nf)
      b0[nf] = *(const bf16x8*)(buf + 16384 + ((bRowBase + nf * 16 * 64) ^ xorb));
    if (t + 3 < NT) STAGE_A(t + 3);
    __builtin_amdgcn_s_barrier();
    asm volatile("s_waitcnt lgkmcnt(0)" ::: "memory");
    __builtin_amdgcn_sched_barrier(0);
    __builtin_amdgcn_s_setprio(1);
#pragma unroll
    for (int mf = 0; mf < 4; ++mf)
#pragma unroll
      for (int nf = 0; nf < 4; ++nf)
        acc[mf][nf] = mfma16(a0[mf], b0[nf], acc[mf][nf]);
    __builtin_amdgcn_s_setprio(0);
    __builtin_amdgcn_s_barrier();
    bf16x8 a1[4];
#pragma unroll
    for (int mf = 0; mf < 4; ++mf)
      a1[mf] = *(const bf16x8*)(buf + ((aRowBase + (4 + mf) * 16 * 64) ^ xorb));
    if (t + 3 < NT) STAGE_B(t + 3);
    __builtin_amdgcn_s_barrier();
    asm volatile("s_waitcnt lgkmcnt(0)" ::: "memory");
    __builtin_amdgcn_sched_barrier(0);
    __builtin_amdgcn_s_setprio(1);
#pragma unroll
    for (int mf = 0; mf < 4; ++mf)
#pragma unroll
      for (int nf = 0; nf < 4; ++nf)
        acc[4 + mf][nf] = mfma16(a1[mf], b0[nf], acc[4 + mf][nf]);
    __builtin_amdgcn_s_setprio(0);
  }
#undef STAGE_A
#undef STAGE_B

#pragma unroll
  for (int mf = 0; mf < 8; ++mf)
#pragma unroll
    for (int nf = 0; nf < 4; ++nf)
#pragma unroll
      for (int r = 0; r < 4; ++r) {
        int rowc = bm * 256 + wr * 128 + mf * 16 + lg * 4 + r;
        int colc = bn * 256 + wc * 64 + nf * 16 + lr;
        float v = acc[mf][nf][r];
        if constexpr (SCALEQ) v *= QSCALE;
        if constexpr (sizeof(OutT) == 2)
          C[(size_t)rowc * N + colc] = (OutT)f2b(v);
        else
          C[(size_t)rowc * N + colc] = v;
      }
}

// ---------------------------------------------------------------------------
// 128x128 tile GEMM — used for fused K/V projection.
template <typename OutT>
__global__ __launch_bounds__(256) void gemm_bt(
    const unsigned short* __restrict__ A, const unsigned short* __restrict__ Bw,
    OutT* __restrict__ C, int M, int N, int K) {
  alignas(16) __shared__ unsigned short As[4][128][8];
  alignas(16) __shared__ unsigned short Bs[4][128][8];
  const int t = threadIdx.x;
  const int lane = t & 63, w = t >> 6;
  const int lr = lane & 15, lg = lane >> 4;
  const int wr = w >> 1, wc = w & 1;

  const int nbn = N >> 7;
  const int nwg = gridDim.x;
  const int bid = blockIdx.x;
  const int swz = (bid & 7) * (nwg >> 3) + (bid >> 3);
  const int bm = swz / nbn, bn = swz % nbn;

  f32x4 acc[4][4];
#pragma unroll
  for (int m = 0; m < 4; ++m)
#pragma unroll
    for (int n = 0; n < 4; ++n) acc[m][n] = (f32x4){0.f, 0.f, 0.f, 0.f};

  const int c0 = t, c1 = 256 + t;
  const int kc0 = c0 >> 7, row0 = c0 & 127;
  const int kc1 = c1 >> 7, row1 = c1 & 127;
  const unsigned short* Ab = A + (size_t)(bm * 128) * K;
  const unsigned short* Bb = Bw + (size_t)(bn * 128) * K;
  char* AsB = (char*)&As[0][0][0];
  char* BsB = (char*)&Bs[0][0][0];
  const int ub0 = (t & 192) * 16;
  const int ub1 = (256 + (t & 192)) * 16;

  for (int k0 = 0; k0 < K; k0 += 32) {
    load16(Ab + (size_t)row0 * K + k0 + kc0 * 8, AsB + ub0);
    load16(Ab + (size_t)row1 * K + k0 + kc1 * 8, AsB + ub1);
    load16(Bb + (size_t)row0 * K + k0 + kc0 * 8, BsB + ub0);
    load16(Bb + (size_t)row1 * K + k0 + kc1 * 8, BsB + ub1);
    __syncthreads();
    bf16x8 af[4], bfr[4];
#pragma unroll
    for (int i = 0; i < 4; ++i)
      af[i] = *(const bf16x8*)&As[lg][wr * 64 + i * 16 + lr][0];
#pragma unroll
    for (int i = 0; i < 4; ++i)
      bfr[i] = *(const bf16x8*)&Bs[lg][wc * 64 + i * 16 + lr][0];
#pragma unroll
    for (int m = 0; m < 4; ++m)
#pragma unroll
      for (int n = 0; n < 4; ++n)
        acc[m][n] = mfma16(af[m], bfr[n], acc[m][n]);
    __syncthreads();
  }

#pragma unroll
  for (int m = 0; m < 4; ++m)
#pragma unroll
    for (int n = 0; n < 4; ++n)
#pragma unroll
      for (int r = 0; r < 4; ++r) {
        int rowc = bm * 128 + wr * 64 + m * 16 + lg * 4 + r;
        int colc = bn * 128 + wc * 64 + n * 16 + lr;
        float v = acc[m][n][r];
        if constexpr (sizeof(OutT) == 2)
          C[(size_t)rowc * N + colc] = (OutT)f2b(v);
        else
          C[(size_t)rowc * N + colc] = v;
      }
}

// ---------------------------------------------------------------------------
// RoPE on K and V from fused XKV (row stride 2048: cols [0,1024)=K, [1024,2048)=V).
__global__ __launch_bounds__(256) void rope_kv(
    const unsigned short* __restrict__ XKV,
    const float* __restrict__ fc, const float* __restrict__ fs,
    unsigned short* __restrict__ Kr, unsigned short* __restrict__ Vt) {
  __shared__ unsigned short Vl[128][66];
  const int t = threadIdx.x;
  const int bid = blockIdx.x;  // bkv*32 + stile
  const int stile = bid & 31, bkv = bid >> 5;
  const int b = bkv >> 3, kvh = bkv & 7;
  const int s0 = stile * 64;
  const int l = t & 63;
  const int jrow = t >> 6;

  for (int j = 0; j < 16; ++j) {
    int s = s0 + j * 4 + jrow;
    ushort2 v = *(const ushort2*)(XKV + (size_t)(b * 2048 + s) * 2048 + kvh * 128 + 2 * l);
    float c = fc[s * 64 + l], sn = fs[s * 64 + l];
    float xr = b2f(v.x), xi = b2f(v.y);
    ushort2 o;
    o.x = f2b(xr * c - xi * sn);
    o.y = f2b(xr * sn + xi * c);
    *(ushort2*)(Kr + ((size_t)bkv * 2048 + s) * 128 + 2 * l) = o;
  }
  for (int j = 0; j < 16; ++j) {
    int ss = j * 4 + jrow;
    int s = s0 + ss;
    ushort2 v = *(const ushort2*)(XKV + (size_t)(b * 2048 + s) * 2048 + 1024 + kvh * 128 + 2 * l);
    float c = fc[s * 64 + l], sn = fs[s * 64 + l];
    float xr = b2f(v.x), xi = b2f(v.y);
    Vl[2 * l][ss] = f2b(xr * c - xi * sn);
    Vl[2 * l + 1][ss] = f2b(xr * sn + xi * c);
  }
  __syncthreads();
  const int d = t >> 1, half = t & 1;
  unsigned short* vdst = Vt + ((size_t)bkv * 128 + d) * 2048 + s0 + half * 32;
#pragma unroll
  for (int e = 0; e < 32; e += 4) {
    ushort4 pk;
    pk.x = Vl[d][half * 32 + e];
    pk.y = Vl[d][half * 32 + e + 1];
    pk.z = Vl[d][half * 32 + e + 2];
    pk.w = Vl[d][half * 32 + e + 3];
    *(ushort4*)(vdst + e) = pk;
  }
}

// ---------------------------------------------------------------------------
// Flash attention, round 6. Grid 1024 = bh(64) x qtile(16); 4 waves x 32 q.
// KVBLK=64 (32 iterations, one vmcnt(0)+barrier each). Chunk-major LDS
// (all b128 reads: byte = lg*stride + lr*16 + const -> conflict-free):
//   K: [16 dchunk][64 k][8]   16KB x2
//   V: [8 kchunk][128 d][8]   16KB x2
//   P: per-wave [8 kc][32 q][8] 4KB x4
// Total 81920B -> 2 blocks/CU. Max-free exp2 softmax, f2b RNE. No setprio.
__global__ __launch_bounds__(256, 2) void attn_fwd(
    const unsigned short* __restrict__ XQ, const unsigned short* __restrict__ Kr,
    const unsigned short* __restrict__ Vt, unsigned short* __restrict__ AO) {
  extern __shared__ char smem[];  // 81920
  char* Ksm = smem;                                      // [2][16384]
  char* Vsm = smem + 32768;                              // [2][16384]
  unsigned short* Ps = (unsigned short*)(smem + 65536);  // [4][8][32][8]
  const int t = threadIdx.x;
  const int lane = t & 63, w = t >> 6;
  const int lr = lane & 15, lg = lane >> 4;

  const int bid = blockIdx.x;
  const int nwg = gridDim.x;  // 1024
  const int swz = (bid & 7) * (nwg >> 3) + (bid >> 3);
  const int qt = swz & 15;
  const int bh = swz >> 4;
  const int b = bh >> 5, h = bh & 31;
  const int bkv = b * 8 + (h >> 2);

  // Q fragments: 32 q-rows (2 x 16), full D=128 in regs
  bf16x8 qf[2][4];
#pragma unroll
  for (int q2 = 0; q2 < 2; ++q2) {
    const unsigned short* qp =
        XQ + ((size_t)(b * 2048 + qt * 128 + w * 32 + q2 * 16 + lr)) * 4096 +
        h * 128 + lg * 8;
#pragma unroll
    for (int dc = 0; dc < 4; ++dc) qf[q2][dc] = *(const bf16x8*)(qp + dc * 32);
  }

  f32x4 acc[2][8];
#pragma unroll
  for (int q2 = 0; q2 < 2; ++q2)
#pragma unroll
    for (int i = 0; i < 8; ++i) acc[q2][i] = (f32x4){0.f, 0.f, 0.f, 0.f};
  float l_[2][4] = {{0.f, 0.f, 0.f, 0.f}, {0.f, 0.f, 0.f, 0.f}};

  const unsigned short* Kbase = Kr + (size_t)bkv * 2048 * 128;
  const unsigned short* Vbase = Vt + (size_t)bkv * 128 * 2048;

  // staging: 1024 chunks of 16B per operand per tile; thread does chunks
  // c = t + j*256, j=0..3.  K: k = c&63, dchunk = c>>6.  V: d = c&127, kc = c>>7.
  int kK[4], dC[4], vD[4], vKc[4], dstb[4];
#pragma unroll
  for (int j = 0; j < 4; ++j) {
    const int c = t + j * 256;
    kK[j] = c & 63;  dC[j] = c >> 6;
    vD[j] = c & 127; vKc[j] = c >> 7;
    dstb[j] = (c & ~63) * 16;
  }

#define STAGE_KV(bufi, kt)                                                    \
  {                                                                           \
    char* kd = Ksm + (bufi)*16384;                                            \
    char* vd = Vsm + (bufi)*16384;                                            \
    _Pragma("unroll") for (int j = 0; j < 4; ++j) {                           \
      load16(Kbase + (size_t)((kt)*64 + kK[j]) * 128 + dC[j] * 8, kd + dstb[j]); \
      load16(Vbase + (size_t)vD[j] * 2048 + (kt)*64 + vKc[j] * 8, vd + dstb[j]); \
    }                                                                         \
  }

  STAGE_KV(0, 0);
  asm volatile("s_waitcnt vmcnt(0)" ::: "memory");
  __builtin_amdgcn_s_barrier();

  unsigned short* Pw = Ps + w * 2048;              // [8 kc][32 q][8]
  const int pbase = (lr >> 3) * 256 + (lr & 7);    // halfword offset

  for (int kt = 0; kt < 32; ++kt) {
    const int cur = kt & 1;
    if (kt < 31) STAGE_KV(cur ^ 1, kt + 1);

    const char* Kc = Ksm + cur * 16384;
    const char* Vc = Vsm + cur * 16384;

    // QK^T + exp2 + P-store, per nf chunk of 16 k (nf = 0..3)
#pragma unroll
    for (int nf = 0; nf < 4; ++nf) {
      f32x4 s0 = (f32x4){0.f, 0.f, 0.f, 0.f};
      f32x4 s1 = (f32x4){0.f, 0.f, 0.f, 0.f};
#pragma unroll
      for (int dc = 0; dc < 4; ++dc) {
        bf16x8 kf =
            *(const bf16x8*)(Kc + ((dc * 4 + lg) * 64 + nf * 16 + lr) * 16);
        s0 = mfma16(qf[0][dc], kf, s0);
        s1 = mfma16(qf[1][dc], kf, s1);
      }
      const int pb = pbase + nf * 512;  // kc = nf*2 + (lr>>3)
#pragma unroll
      for (int r = 0; r < 4; ++r) {
        float p0 = __builtin_amdgcn_exp2f(s0[r]);
        float p1 = __builtin_amdgcn_exp2f(s1[r]);
        l_[0][r] += p0;
        l_[1][r] += p1;
        Pw[pb + (lg * 4 + r) * 8] = f2b(p0);
        Pw[pb + (16 + lg * 4 + r) * 8] = f2b(p1);
      }
    }

    // PV over two 32-k halves: kc = ks*4 + lg
#pragma unroll
    for (int ks = 0; ks < 2; ++ks) {
      bf16x8 pf0 = *(const bf16x8*)(Pw + (ks * 4 + lg) * 256 + lr * 8);
      bf16x8 pf1 = *(const bf16x8*)(Pw + (ks * 4 + lg) * 256 + (16 + lr) * 8);
#pragma unroll
      for (int dt = 0; dt < 8; ++dt) {
        bf16x8 vf =
            *(const bf16x8*)(Vc + ((ks * 4 + lg) * 128 + dt * 16 + lr) * 16);
        acc[0][dt] = mfma16(pf0, vf, acc[0][dt]);
        acc[1][dt] = mfma16(pf1, vf, acc[1][dt]);
      }
    }

    asm volatile("s_waitcnt vmcnt(0)" ::: "memory");
    __builtin_amdgcn_s_barrier();
  }
#undef STAGE_KV

  // reduce l across the 16 lanes of each lg row-group
#pragma unroll
  for (int q2 = 0; q2 < 2; ++q2)
#pragma unroll
    for (int r = 0; r < 4; ++r) {
#pragma unroll
      for (int o = 1; o < 16; o <<= 1) l_[q2][r] += __shfl_xor(l_[q2][r], o);
    }

#pragma unroll
  for (int q2 = 0; q2 < 2; ++q2)
#pragma unroll
    for (int r = 0; r < 4; ++r) {
      float inv = 1.f / l_[q2][r];
      size_t rowb =
          ((size_t)(b * 2048 + qt * 128 + w * 32 + q2 * 16 + lg * 4 + r)) * 4096 +
          h * 128;
#pragma unroll
      for (int dt = 0; dt < 8; ++dt)
        AO[rowb + dt * 16 + lr] = f2b(acc[q2][dt][r] * inv);
    }
}

// ---------------------------------------------------------------------------
extern "C" void kernel_launch(void* const* d_in, const int* in_sizes, int n_in,
                              void* d_out, int out_size, void* d_ws, size_t ws_size,
                              hipStream_t stream) {
  const float* x  = (const float*)d_in[0];
  const float* fc = (const float*)d_in[2];
  const float* fs = (const float*)d_in[3];
  const float* wq = (const float*)d_in[4];
  const float* wk = (const float*)d_in[5];
  const float* wv = (const float*)d_in[6];
  const float* wo = (const float*)d_in[7];

  const size_t MB = 1024ull * 1024ull;
  char* ws = (char*)d_ws;
  unsigned short* Xb  = (unsigned short*)(ws);
  unsigned short* Wsc = (unsigned short*)(ws + 32 * MB);
  unsigned short* XKV = (unsigned short*)(ws + 64 * MB);  // 4096 x 2048 (16MB)
  unsigned short* Kr  = (unsigned short*)(ws);            // reuse Xb region
  unsigned short* Vt  = (unsigned short*)(ws + 8 * MB);
  unsigned short* AO  = (unsigned short*)(ws + 80 * MB);
  unsigned short* XQ  = (unsigned short*)d_out;

  (void)hipFuncSetAttribute((const void*)gemm256<unsigned short, true>,
                            hipFuncAttributeMaxDynamicSharedMemorySize, 131072);
  (void)hipFuncSetAttribute((const void*)gemm256<float, false>,
                            hipFuncAttributeMaxDynamicSharedMemorySize, 131072);
  (void)hipFuncSetAttribute((const void*)attn_fwd,
                            hipFuncAttributeMaxDynamicSharedMemorySize, 81920);

  dim3 blk(256);
  dim3 blk512(512);
  cvt_f32_bf16<<<2048, blk, 0, stream>>>(x, Xb, (2 * 2048 * 4096) / 4);
  cvt_f32_bf16<<<2048, blk, 0, stream>>>(wq, Wsc, (4096 * 4096) / 4);
  gemm256<unsigned short, true><<<256, blk512, 131072, stream>>>(
      Xb, Wsc, XQ, 4096, 4096, 4096);
  cvt_f32_bf16<<<2048, blk, 0, stream>>>(wk, Wsc, (1024 * 4096) / 4);
  cvt_f32_bf16<<<2048, blk, 0, stream>>>(wv, Wsc + 1024 * 4096, (1024 * 4096) / 4);
  gemm_bt<unsigned short><<<512, blk, 0, stream>>>(Xb, Wsc, XKV, 4096, 2048, 4096);
  rope_kv<<<512, blk, 0, stream>>>(XKV, fc, fs, Kr, Vt);
  attn_fwd<<<1024, blk, 81920, stream>>>(XQ, Kr, Vt, AO);
  cvt_f32_bf16<<<2048, blk, 0, stream>>>(wo, Wsc, (4096 * 4096) / 4);
  gemm256<float, false><<<256, blk512, 131072, stream>>>(
      AO, Wsc, (float*)d_out, 4096, 4096, 4096);
}

// Round 7
// 597.618 us; speedup vs baseline: 1.1173x; 1.0356x over previous
//
#include <hip/hip_runtime.h>

// ---------------------------------------------------------------------------
// SelfAttention (B=2,S=2048,D=4096, NH=32,NKV=8,HD=128, NREP=4, non-causal)
// RoPE on K and V (reference quirk), NOT on Q.
// Round 7: gemm256 rewritten as BK=64 / 2-buffer / 4-phase (m201-style):
//   per phase {ds_read subtile + stage -> barrier -> lgkm(0) -> setprio ->
//   16 MFMA -> setprio -> barrier}; one far-gated vmcnt(0) per K-tile;
//   row-XOR-8 LDS swizzle (2 lanes/bank, conflict-free) with pre-swizzled
//   global source + linear global_load_lds dest. Attn unchanged from r6.
// ---------------------------------------------------------------------------

typedef short bf16x8 __attribute__((ext_vector_type(8)));
typedef float f32x4 __attribute__((ext_vector_type(4)));

__device__ __forceinline__ void load16(const void* g, void* l) {
  __builtin_amdgcn_global_load_lds(
      (const __attribute__((address_space(1))) void*)g,
      (__attribute__((address_space(3))) void*)l, 16, 0, 0);
}

__device__ __forceinline__ f32x4 mfma16(bf16x8 a, bf16x8 b, f32x4 c) {
  return __builtin_amdgcn_mfma_f32_16x16x32_bf16(a, b, c, 0, 0, 0);
}

__device__ __forceinline__ unsigned short f2b(float f) {
  union { float f; unsigned int u; } v; v.f = f;
  unsigned int u = v.u;
  return (unsigned short)((u + 0x7fffu + ((u >> 16) & 1u)) >> 16);
}
__device__ __forceinline__ float b2f(unsigned short u) {
  union { unsigned int u; float f; } v; v.u = ((unsigned int)u) << 16;
  return v.f;
}

// softmax scale folded with log2(e) so attention uses exp2 directly
#define QSCALE (0.08838834764831845f * 1.4426950408889634f)

// ---------------------------------------------------------------------------
__global__ __launch_bounds__(256) void cvt_f32_bf16(
    const float* __restrict__ in, unsigned short* __restrict__ out, int n4) {
  int idx = blockIdx.x * 256 + threadIdx.x;
  int stride = gridDim.x * 256;
  for (int i = idx; i < n4; i += stride) {
    float4 v = reinterpret_cast<const float4*>(in)[i];
    ushort4 o;
    o.x = f2b(v.x); o.y = f2b(v.y); o.z = f2b(v.z); o.w = f2b(v.w);
    reinterpret_cast<ushort4*>(out)[i] = o;
  }
}

// ---------------------------------------------------------------------------
// 256x256 tile, BK=64, 8 waves (2Mx4N), per-wave 128x64 output.
// LDS: 2 buffers x (A[256][64] + B[256][64]) = 131072 B. Row = 128 B,
// swizzle byte ^= ((row&7)<<4): every ds_read_b128 frag lands 2 lanes/bank.
// Staging: linear global_load_lds dest, source k-offset pre-swizzled by the
// same involution (16B granule aligned). 4 phases of 16 MFMA per K-tile:
//   ph0: read A m0-3 + B n0-1 (12), stage next-B j0-3 ; MFMA m0-3 x n0-1
//   ph1: read B n2-3 (4),           stage next-A j0-3 ; MFMA m0-3 x n2-3
//   ph2: read A m4-7 (8)                              ; MFMA m4-7 x n0-1
//   ph3: (no reads)                                   ; MFMA m4-7 x n2-3
// Gate: vmcnt(0)+barrier once per tile; its loads were issued ~3 phases ago.
template <typename OutT, bool SCALEQ>
__global__ __launch_bounds__(512, 2) void gemm256(
    const unsigned short* __restrict__ A, const unsigned short* __restrict__ Bw,
    OutT* __restrict__ C, int M, int N, int K) {
  extern __shared__ char smem[];  // 131072 bytes
  const int tid = threadIdx.x;
  const int lane = tid & 63;
  const int w = tid >> 6;
  const int lr = lane & 15, lg = lane >> 4;
  const int wr = w >> 2, wc = w & 3;

  const int nbn = N >> 8;
  const int bid = blockIdx.x, nwg = gridDim.x;
  const int swz = (bid & 7) * (nwg >> 3) + (bid >> 3);  // nwg % 8 == 0
  const int bm = swz / nbn, bn = swz % nbn;

  const unsigned short* Ag = A + (size_t)bm * 256 * K;
  const unsigned short* Bg = Bw + (size_t)bn * 256 * K;

  // staging: 4 loads/thread per operand per tile; chunk c = tid + j*512
  // dest byte L = c*16 (linear); row = c>>3, slot = c&7;
  // source halfword = row*K + t*64 + ((slot ^ (row&7))<<3)
  int srow[4], skhw[4], sdst[4];
#pragma unroll
  for (int j = 0; j < 4; ++j) {
    const int c = tid + j * 512;
    srow[j] = c >> 3;
    skhw[j] = ((c & 7) ^ ((c >> 3) & 7)) << 3;
    sdst[j] = ((tid & ~63) << 4) + j * 8192;  // wave-uniform LDS byte base
  }

  f32x4 acc[8][4];
#pragma unroll
  for (int m = 0; m < 8; ++m)
#pragma unroll
    for (int n = 0; n < 4; ++n) acc[m][n] = (f32x4){0.f, 0.f, 0.f, 0.f};

#define STAGEA4(tt)                                                           \
  {                                                                           \
    char* d = smem + (((tt)&1) * 65536);                                      \
    _Pragma("unroll") for (int j = 0; j < 4; ++j)                             \
        load16(Ag + (size_t)srow[j] * K + ((tt) << 6) + skhw[j], d + sdst[j]);\
  }
#define STAGEB4(tt)                                                           \
  {                                                                           \
    char* d = smem + (((tt)&1) * 65536) + 32768;                              \
    _Pragma("unroll") for (int j = 0; j < 4; ++j)                             \
        load16(Bg + (size_t)srow[j] * K + ((tt) << 6) + skhw[j], d + sdst[j]);\
  }

  // prologue: stage tile 0 (16 loads)
  STAGEB4(0);
  STAGEA4(0);

  const int NT = K >> 6;
  const int rx = (lr & 7) << 4;
  const int aRow0 = (wr * 128 + lr) * 128;
  const int bRow0 = (wc * 64 + lr) * 128;
  const int col0 = (lg * 16) ^ rx;        // ks = 0
  const int col1 = (64 + lg * 16) ^ rx;   // ks = 1

  bf16x8 aR[4][2], bR[4][2];

  for (int t = 0; t < NT; ++t) {
    const char* bufA = smem + (t & 1) * 65536;
    const char* bufB = bufA + 32768;
    const bool more = (t + 1) < NT;

    // gate: tile t's 16 loads (issued during tile t-1 ph0/ph1) complete
    asm volatile("s_waitcnt vmcnt(0)" ::: "memory");
    __builtin_amdgcn_s_barrier();

    // ---- ph0: A m0-3 (8 reads) + B n0-1 (4 reads); stage next B ----
#pragma unroll
    for (int mf = 0; mf < 4; ++mf) {
      aR[mf][0] = *(const bf16x8*)(bufA + aRow0 + mf * 2048 + col0);
      aR[mf][1] = *(const bf16x8*)(bufA + aRow0 + mf * 2048 + col1);
    }
#pragma unroll
    for (int nf = 0; nf < 2; ++nf) {
      bR[nf][0] = *(const bf16x8*)(bufB + bRow0 + nf * 2048 + col0);
      bR[nf][1] = *(const bf16x8*)(bufB + bRow0 + nf * 2048 + col1);
    }
    if (more) STAGEB4(t + 1);
    asm volatile("s_waitcnt lgkmcnt(8)" ::: "memory");
    __builtin_amdgcn_s_barrier();
    asm volatile("s_waitcnt lgkmcnt(0)" ::: "memory");
    __builtin_amdgcn_sched_barrier(0);
    __builtin_amdgcn_s_setprio(1);
#pragma unroll
    for (int mf = 0; mf < 4; ++mf)
#pragma unroll
      for (int nf = 0; nf < 2; ++nf) {
        acc[mf][nf] = mfma16(aR[mf][0], bR[nf][0], acc[mf][nf]);
        acc[mf][nf] = mfma16(aR[mf][1], bR[nf][1], acc[mf][nf]);
      }
    __builtin_amdgcn_s_setprio(0);
    __builtin_amdgcn_s_barrier();

    // ---- ph1: B n2-3 (4 reads); stage next A ----
#pragma unroll
    for (int nf = 2; nf < 4; ++nf) {
      bR[nf][0] = *(const bf16x8*)(bufB + bRow0 + nf * 2048 + col0);
      bR[nf][1] = *(const bf16x8*)(bufB + bRow0 + nf * 2048 + col1);
    }
    if (more) STAGEA4(t + 1);
    __builtin_amdgcn_s_barrier();
    asm volatile("s_waitcnt lgkmcnt(0)" ::: "memory");
    __builtin_amdgcn_sched_barrier(0);
    __builtin_amdgcn_s_setprio(1);
#pragma unroll
    for (int mf = 0; mf < 4; ++mf)
#pragma unroll
      for (int nf = 2; nf < 4; ++nf) {
        acc[mf][nf] = mfma16(aR[mf][0], bR[nf][0], acc[mf][nf]);
        acc[mf][nf] = mfma16(aR[mf][1], bR[nf][1], acc[mf][nf]);
      }
    __builtin_amdgcn_s_setprio(0);
    __builtin_amdgcn_s_barrier();

    // ---- ph2: A m4-7 (8 reads, reuse aR regs) ----
#pragma unroll
    for (int mf = 0; mf < 4; ++mf) {
      aR[mf][0] = *(const bf16x8*)(bufA + aRow0 + (4 + mf) * 2048 + col0);
      aR[mf][1] = *(const bf16x8*)(bufA + aRow0 + (4 + mf) * 2048 + col1);
    }
    __builtin_amdgcn_s_barrier();
    asm volatile("s_waitcnt lgkmcnt(0)" ::: "memory");
    __builtin_amdgcn_sched_barrier(0);
    __builtin_amdgcn_s_setprio(1);
#pragma unroll
    for (int mf = 0; mf < 4; ++mf)
#pragma unroll
      for (int nf = 0; nf < 2; ++nf) {
        acc[4 + mf][nf] = mfma16(aR[mf][0], bR[nf][0], acc[4 + mf][nf]);
        acc[4 + mf][nf] = mfma16(aR[mf][1], bR[nf][1], acc[4 + mf][nf]);
      }
    __builtin_amdgcn_s_setprio(0);
    __builtin_amdgcn_s_barrier();

    // ---- ph3: no reads; MFMA m4-7 x n2-3 ----
    __builtin_amdgcn_s_setprio(1);
#pragma unroll
    for (int mf = 0; mf < 4; ++mf)
#pragma unroll
      for (int nf = 2; nf < 4; ++nf) {
        acc[4 + mf][nf] = mfma16(aR[mf][0], bR[nf][0], acc[4 + mf][nf]);
        acc[4 + mf][nf] = mfma16(aR[mf][1], bR[nf][1], acc[4 + mf][nf]);
      }
    __builtin_amdgcn_s_setprio(0);
    // next iteration's vmcnt(0)+barrier is the tile boundary
  }
#undef STAGEA4
#undef STAGEB4

#pragma unroll
  for (int mf = 0; mf < 8; ++mf)
#pragma unroll
    for (int nf = 0; nf < 4; ++nf)
#pragma unroll
      for (int r = 0; r < 4; ++r) {
        int rowc = bm * 256 + wr * 128 + mf * 16 + lg * 4 + r;
        int colc = bn * 256 + wc * 64 + nf * 16 + lr;
        float v = acc[mf][nf][r];
        if constexpr (SCALEQ) v *= QSCALE;
        if constexpr (sizeof(OutT) == 2)
          C[(size_t)rowc * N + colc] = (OutT)f2b(v);
        else
          C[(size_t)rowc * N + colc] = v;
      }
}

// ---------------------------------------------------------------------------
// 128x128 tile GEMM — used for fused K/V projection.
template <typename OutT>
__global__ __launch_bounds__(256) void gemm_bt(
    const unsigned short* __restrict__ A, const unsigned short* __restrict__ Bw,
    OutT* __restrict__ C, int M, int N, int K) {
  alignas(16) __shared__ unsigned short As[4][128][8];
  alignas(16) __shared__ unsigned short Bs[4][128][8];
  const int t = threadIdx.x;
  const int lane = t & 63, w = t >> 6;
  const int lr = lane & 15, lg = lane >> 4;
  const int wr = w >> 1, wc = w & 1;

  const int nbn = N >> 7;
  const int nwg = gridDim.x;
  const int bid = blockIdx.x;
  const int swz = (bid & 7) * (nwg >> 3) + (bid >> 3);
  const int bm = swz / nbn, bn = swz % nbn;

  f32x4 acc[4][4];
#pragma unroll
  for (int m = 0; m < 4; ++m)
#pragma unroll
    for (int n = 0; n < 4; ++n) acc[m][n] = (f32x4){0.f, 0.f, 0.f, 0.f};

  const int c0 = t, c1 = 256 + t;
  const int kc0 = c0 >> 7, row0 = c0 & 127;
  const int kc1 = c1 >> 7, row1 = c1 & 127;
  const unsigned short* Ab = A + (size_t)(bm * 128) * K;
  const unsigned short* Bb = Bw + (size_t)(bn * 128) * K;
  char* AsB = (char*)&As[0][0][0];
  char* BsB = (char*)&Bs[0][0][0];
  const int ub0 = (t & 192) * 16;
  const int ub1 = (256 + (t & 192)) * 16;

  for (int k0 = 0; k0 < K; k0 += 32) {
    load16(Ab + (size_t)row0 * K + k0 + kc0 * 8, AsB + ub0);
    load16(Ab + (size_t)row1 * K + k0 + kc1 * 8, AsB + ub1);
    load16(Bb + (size_t)row0 * K + k0 + kc0 * 8, BsB + ub0);
    load16(Bb + (size_t)row1 * K + k0 + kc1 * 8, BsB + ub1);
    __syncthreads();
    bf16x8 af[4], bfr[4];
#pragma unroll
    for (int i = 0; i < 4; ++i)
      af[i] = *(const bf16x8*)&As[lg][wr * 64 + i * 16 + lr][0];
#pragma unroll
    for (int i = 0; i < 4; ++i)
      bfr[i] = *(const bf16x8*)&Bs[lg][wc * 64 + i * 16 + lr][0];
#pragma unroll
    for (int m = 0; m < 4; ++m)
#pragma unroll
      for (int n = 0; n < 4; ++n)
        acc[m][n] = mfma16(af[m], bfr[n], acc[m][n]);
    __syncthreads();
  }

#pragma unroll
  for (int m = 0; m < 4; ++m)
#pragma unroll
    for (int n = 0; n < 4; ++n)
#pragma unroll
      for (int r = 0; r < 4; ++r) {
        int rowc = bm * 128 + wr * 64 + m * 16 + lg * 4 + r;
        int colc = bn * 128 + wc * 64 + n * 16 + lr;
        float v = acc[m][n][r];
        if constexpr (sizeof(OutT) == 2)
          C[(size_t)rowc * N + colc] = (OutT)f2b(v);
        else
          C[(size_t)rowc * N + colc] = v;
      }
}

// ---------------------------------------------------------------------------
// RoPE on K and V from fused XKV (row stride 2048: cols [0,1024)=K, [1024,2048)=V).
__global__ __launch_bounds__(256) void rope_kv(
    const unsigned short* __restrict__ XKV,
    const float* __restrict__ fc, const float* __restrict__ fs,
    unsigned short* __restrict__ Kr, unsigned short* __restrict__ Vt) {
  __shared__ unsigned short Vl[128][66];
  const int t = threadIdx.x;
  const int bid = blockIdx.x;  // bkv*32 + stile
  const int stile = bid & 31, bkv = bid >> 5;
  const int b = bkv >> 3, kvh = bkv & 7;
  const int s0 = stile * 64;
  const int l = t & 63;
  const int jrow = t >> 6;

  for (int j = 0; j < 16; ++j) {
    int s = s0 + j * 4 + jrow;
    ushort2 v = *(const ushort2*)(XKV + (size_t)(b * 2048 + s) * 2048 + kvh * 128 + 2 * l);
    float c = fc[s * 64 + l], sn = fs[s * 64 + l];
    float xr = b2f(v.x), xi = b2f(v.y);
    ushort2 o;
    o.x = f2b(xr * c - xi * sn);
    o.y = f2b(xr * sn + xi * c);
    *(ushort2*)(Kr + ((size_t)bkv * 2048 + s) * 128 + 2 * l) = o;
  }
  for (int j = 0; j < 16; ++j) {
    int ss = j * 4 + jrow;
    int s = s0 + ss;
    ushort2 v = *(const ushort2*)(XKV + (size_t)(b * 2048 + s) * 2048 + 1024 + kvh * 128 + 2 * l);
    float c = fc[s * 64 + l], sn = fs[s * 64 + l];
    float xr = b2f(v.x), xi = b2f(v.y);
    Vl[2 * l][ss] = f2b(xr * c - xi * sn);
    Vl[2 * l + 1][ss] = f2b(xr * sn + xi * c);
  }
  __syncthreads();
  const int d = t >> 1, half = t & 1;
  unsigned short* vdst = Vt + ((size_t)bkv * 128 + d) * 2048 + s0 + half * 32;
#pragma unroll
  for (int e = 0; e < 32; e += 4) {
    ushort4 pk;
    pk.x = Vl[d][half * 32 + e];
    pk.y = Vl[d][half * 32 + e + 1];
    pk.z = Vl[d][half * 32 + e + 2];
    pk.w = Vl[d][half * 32 + e + 3];
    *(ushort4*)(vdst + e) = pk;
  }
}

// ---------------------------------------------------------------------------
// Flash attention (round-6 kernel, unchanged). Grid 1024; 4 waves x 32 q.
// KVBLK=64; chunk-major conflict-free LDS; 80KB -> 2 blocks/CU.
__global__ __launch_bounds__(256, 2) void attn_fwd(
    const unsigned short* __restrict__ XQ, const unsigned short* __restrict__ Kr,
    const unsigned short* __restrict__ Vt, unsigned short* __restrict__ AO) {
  extern __shared__ char smem[];  // 81920
  char* Ksm = smem;                                      // [2][16384]
  char* Vsm = smem + 32768;                              // [2][16384]
  unsigned short* Ps = (unsigned short*)(smem + 65536);  // [4][8][32][8]
  const int t = threadIdx.x;
  const int lane = t & 63, w = t >> 6;
  const int lr = lane & 15, lg = lane >> 4;

  const int bid = blockIdx.x;
  const int nwg = gridDim.x;  // 1024
  const int swz = (bid & 7) * (nwg >> 3) + (bid >> 3);
  const int qt = swz & 15;
  const int bh = swz >> 4;
  const int b = bh >> 5, h = bh & 31;
  const int bkv = b * 8 + (h >> 2);

  bf16x8 qf[2][4];
#pragma unroll
  for (int q2 = 0; q2 < 2; ++q2) {
    const unsigned short* qp =
        XQ + ((size_t)(b * 2048 + qt * 128 + w * 32 + q2 * 16 + lr)) * 4096 +
        h * 128 + lg * 8;
#pragma unroll
    for (int dc = 0; dc < 4; ++dc) qf[q2][dc] = *(const bf16x8*)(qp + dc * 32);
  }

  f32x4 acc[2][8];
#pragma unroll
  for (int q2 = 0; q2 < 2; ++q2)
#pragma unroll
    for (int i = 0; i < 8; ++i) acc[q2][i] = (f32x4){0.f, 0.f, 0.f, 0.f};
  float l_[2][4] = {{0.f, 0.f, 0.f, 0.f}, {0.f, 0.f, 0.f, 0.f}};

  const unsigned short* Kbase = Kr + (size_t)bkv * 2048 * 128;
  const unsigned short* Vbase = Vt + (size_t)bkv * 128 * 2048;

  int kK[4], dC[4], vD[4], vKc[4], dstb[4];
#pragma unroll
  for (int j = 0; j < 4; ++j) {
    const int c = t + j * 256;
    kK[j] = c & 63;  dC[j] = c >> 6;
    vD[j] = c & 127; vKc[j] = c >> 7;
    dstb[j] = (c & ~63) * 16;
  }

#define STAGE_KV(bufi, kt)                                                    \
  {                                                                           \
    char* kd = Ksm + (bufi)*16384;                                            \
    char* vd = Vsm + (bufi)*16384;                                            \
    _Pragma("unroll") for (int j = 0; j < 4; ++j) {                           \
      load16(Kbase + (size_t)((kt)*64 + kK[j]) * 128 + dC[j] * 8, kd + dstb[j]); \
      load16(Vbase + (size_t)vD[j] * 2048 + (kt)*64 + vKc[j] * 8, vd + dstb[j]); \
    }                                                                         \
  }

  STAGE_KV(0, 0);
  asm volatile("s_waitcnt vmcnt(0)" ::: "memory");
  __builtin_amdgcn_s_barrier();

  unsigned short* Pw = Ps + w * 2048;              // [8 kc][32 q][8]
  const int pbase = (lr >> 3) * 256 + (lr & 7);    // halfword offset

  for (int kt = 0; kt < 32; ++kt) {
    const int cur = kt & 1;
    if (kt < 31) STAGE_KV(cur ^ 1, kt + 1);

    const char* Kc = Ksm + cur * 16384;
    const char* Vc = Vsm + cur * 16384;

#pragma unroll
    for (int nf = 0; nf < 4; ++nf) {
      f32x4 s0 = (f32x4){0.f, 0.f, 0.f, 0.f};
      f32x4 s1 = (f32x4){0.f, 0.f, 0.f, 0.f};
#pragma unroll
      for (int dc = 0; dc < 4; ++dc) {
        bf16x8 kf =
            *(const bf16x8*)(Kc + ((dc * 4 + lg) * 64 + nf * 16 + lr) * 16);
        s0 = mfma16(qf[0][dc], kf, s0);
        s1 = mfma16(qf[1][dc], kf, s1);
      }
      const int pb = pbase + nf * 512;  // kc = nf*2 + (lr>>3)
#pragma unroll
      for (int r = 0; r < 4; ++r) {
        float p0 = __builtin_amdgcn_exp2f(s0[r]);
        float p1 = __builtin_amdgcn_exp2f(s1[r]);
        l_[0][r] += p0;
        l_[1][r] += p1;
        Pw[pb + (lg * 4 + r) * 8] = f2b(p0);
        Pw[pb + (16 + lg * 4 + r) * 8] = f2b(p1);
      }
    }

#pragma unroll
    for (int ks = 0; ks < 2; ++ks) {
      bf16x8 pf0 = *(const bf16x8*)(Pw + (ks * 4 + lg) * 256 + lr * 8);
      bf16x8 pf1 = *(const bf16x8*)(Pw + (ks * 4 + lg) * 256 + (16 + lr) * 8);
#pragma unroll
      for (int dt = 0; dt < 8; ++dt) {
        bf16x8 vf =
            *(const bf16x8*)(Vc + ((ks * 4 + lg) * 128 + dt * 16 + lr) * 16);
        acc[0][dt] = mfma16(pf0, vf, acc[0][dt]);
        acc[1][dt] = mfma16(pf1, vf, acc[1][dt]);
      }
    }

    asm volatile("s_waitcnt vmcnt(0)" ::: "memory");
    __builtin_amdgcn_s_barrier();
  }
#undef STAGE_KV

#pragma unroll
  for (int q2 = 0; q2 < 2; ++q2)
#pragma unroll
    for (int r = 0; r < 4; ++r) {
#pragma unroll
      for (int o = 1; o < 16; o <<= 1) l_[q2][r] += __shfl_xor(l_[q2][r], o);
    }

#pragma unroll
  for (int q2 = 0; q2 < 2; ++q2)
#pragma unroll
    for (int r = 0; r < 4; ++r) {
      float inv = 1.f / l_[q2][r];
      size_t rowb =
          ((size_t)(b * 2048 + qt * 128 + w * 32 + q2 * 16 + lg * 4 + r)) * 4096 +
          h * 128;
#pragma unroll
      for (int dt = 0; dt < 8; ++dt)
        AO[rowb + dt * 16 + lr] = f2b(acc[q2][dt][r] * inv);
    }
}

// ---------------------------------------------------------------------------
extern "C" void kernel_launch(void* const* d_in, const int* in_sizes, int n_in,
                              void* d_out, int out_size, void* d_ws, size_t ws_size,
                              hipStream_t stream) {
  const float* x  = (const float*)d_in[0];
  const float* fc = (const float*)d_in[2];
  const float* fs = (const float*)d_in[3];
  const float* wq = (const float*)d_in[4];
  const float* wk = (const float*)d_in[5];
  const float* wv = (const float*)d_in[6];
  const float* wo = (const float*)d_in[7];

  const size_t MB = 1024ull * 1024ull;
  char* ws = (char*)d_ws;
  unsigned short* Xb  = (unsigned short*)(ws);
  unsigned short* Wsc = (unsigned short*)(ws + 32 * MB);
  unsigned short* XKV = (unsigned short*)(ws + 64 * MB);  // 4096 x 2048 (16MB)
  unsigned short* Kr  = (unsigned short*)(ws);            // reuse Xb region
  unsigned short* Vt  = (unsigned short*)(ws + 8 * MB);
  unsigned short* AO  = (unsigned short*)(ws + 80 * MB);
  unsigned short* XQ  = (unsigned short*)d_out;

  (void)hipFuncSetAttribute((const void*)gemm256<unsigned short, true>,
                            hipFuncAttributeMaxDynamicSharedMemorySize, 131072);
  (void)hipFuncSetAttribute((const void*)gemm256<float, false>,
                            hipFuncAttributeMaxDynamicSharedMemorySize, 131072);
  (void)hipFuncSetAttribute((const void*)attn_fwd,
                            hipFuncAttributeMaxDynamicSharedMemorySize, 81920);

  dim3 blk(256);
  dim3 blk512(512);
  cvt_f32_bf16<<<2048, blk, 0, stream>>>(x, Xb, (2 * 2048 * 4096) / 4);
  cvt_f32_bf16<<<2048, blk, 0, stream>>>(wq, Wsc, (4096 * 4096) / 4);
  gemm256<unsigned short, true><<<256, blk512, 131072, stream>>>(
      Xb, Wsc, XQ, 4096, 4096, 4096);
  cvt_f32_bf16<<<2048, blk, 0, stream>>>(wk, Wsc, (1024 * 4096) / 4);
  cvt_f32_bf16<<<2048, blk, 0, stream>>>(wv, Wsc + 1024 * 4096, (1024 * 4096) / 4);
  gemm_bt<unsigned short><<<512, blk, 0, stream>>>(Xb, Wsc, XKV, 4096, 2048, 4096);
  rope_kv<<<512, blk, 0, stream>>>(XKV, fc, fs, Kr, Vt);
  attn_fwd<<<1024, blk, 81920, stream>>>(XQ, Kr, Vt, AO);
  cvt_f32_bf16<<<2048, blk, 0, stream>>>(wo, Wsc, (4096 * 4096) / 4);
  gemm256<float, false><<<256, blk512, 131072, stream>>>(
      AO, Wsc, (float*)d_out, 4096, 4096, 4096);
}

// Round 8
// 563.225 us; speedup vs baseline: 1.1855x; 1.0611x over previous
//
#include <hip/hip_runtime.h>
#include <hip/hip_bf16.h>

// ---------------------------------------------------------------------------
// SelfAttention (B=2,S=2048,D=4096, NH=32,NKV=8,HD=128, NREP=4, non-causal)
// RoPE on K and V (reference quirk), NOT on Q.
// Round 8:
//  - Q,K,V projections fused into ONE gemm256 (M=4096,N=6144, grid 384);
//    XQKV (bf16, 48MB) lives in d_out; QSCALE applied when bn<16.
//  - attn: f2b bit-twiddle replaced by native __float2bfloat16 (VALU cut);
//    XQ row stride 6144.
// Workspace: Xb [0,32)MB (dead after QKV gemm; Kr [0,8) Vt [8,16) reuse it),
//            Wsc [32,80)MB (wq|wk|wv then wo), AO [80,112)MB.
// ---------------------------------------------------------------------------

typedef short bf16x8 __attribute__((ext_vector_type(8)));
typedef float f32x4 __attribute__((ext_vector_type(4)));

__device__ __forceinline__ void load16(const void* g, void* l) {
  __builtin_amdgcn_global_load_lds(
      (const __attribute__((address_space(1))) void*)g,
      (__attribute__((address_space(3))) void*)l, 16, 0, 0);
}

__device__ __forceinline__ f32x4 mfma16(bf16x8 a, bf16x8 b, f32x4 c) {
  return __builtin_amdgcn_mfma_f32_16x16x32_bf16(a, b, c, 0, 0, 0);
}

__device__ __forceinline__ unsigned short f2b(float f) {
  union { float f; unsigned int u; } v; v.f = f;
  unsigned int u = v.u;
  return (unsigned short)((u + 0x7fffu + ((u >> 16) & 1u)) >> 16);
}
__device__ __forceinline__ float b2f(unsigned short u) {
  union { unsigned int u; float f; } v; v.u = ((unsigned int)u) << 16;
  return v.f;
}
// native RNE fp32->bf16 (compiler emits v_cvt_*, m240: cheaper than bit-ops)
__device__ __forceinline__ unsigned short f2b_fast(float f) {
  __hip_bfloat16 h = __float2bfloat16(f);
  return *reinterpret_cast<unsigned short*>(&h);
}

// softmax scale folded with log2(e) so attention uses exp2 directly
#define QSCALE (0.08838834764831845f * 1.4426950408889634f)

// ---------------------------------------------------------------------------
__global__ __launch_bounds__(256) void cvt_f32_bf16(
    const float* __restrict__ in, unsigned short* __restrict__ out, int n4) {
  int idx = blockIdx.x * 256 + threadIdx.x;
  int stride = gridDim.x * 256;
  for (int i = idx; i < n4; i += stride) {
    float4 v = reinterpret_cast<const float4*>(in)[i];
    ushort4 o;
    o.x = f2b(v.x); o.y = f2b(v.y); o.z = f2b(v.z); o.w = f2b(v.w);
    reinterpret_cast<ushort4*>(out)[i] = o;
  }
}

// ---------------------------------------------------------------------------
// 256x256 tile, BK=64, 8 waves (2Mx4N), per-wave 128x64 output.
// LDS: 2 buffers x (A[256][64] + B[256][64]) = 131072 B, row-XOR-8 swizzle.
// 4 phases of 16 MFMA per K-tile; one vmcnt(0) gate per tile (far-issued).
// sbl: C column-blocks bn < sbl get QSCALE (block-uniform).
template <typename OutT>
__global__ __launch_bounds__(512, 2) void gemm256(
    const unsigned short* __restrict__ A, const unsigned short* __restrict__ Bw,
    OutT* __restrict__ C, int M, int N, int K, int sbl) {
  extern __shared__ char smem[];  // 131072 bytes
  const int tid = threadIdx.x;
  const int lane = tid & 63;
  const int w = tid >> 6;
  const int lr = lane & 15, lg = lane >> 4;
  const int wr = w >> 2, wc = w & 3;

  const int nbn = N >> 8;
  const int bid = blockIdx.x, nwg = gridDim.x;
  const int swz = (bid & 7) * (nwg >> 3) + (bid >> 3);  // nwg % 8 == 0
  const int bm = swz / nbn, bn = swz % nbn;

  const unsigned short* Ag = A + (size_t)bm * 256 * K;
  const unsigned short* Bg = Bw + (size_t)bn * 256 * K;

  int srow[4], skhw[4], sdst[4];
#pragma unroll
  for (int j = 0; j < 4; ++j) {
    const int c = tid + j * 512;
    srow[j] = c >> 3;
    skhw[j] = ((c & 7) ^ ((c >> 3) & 7)) << 3;
    sdst[j] = ((tid & ~63) << 4) + j * 8192;  // wave-uniform LDS byte base
  }

  f32x4 acc[8][4];
#pragma unroll
  for (int m = 0; m < 8; ++m)
#pragma unroll
    for (int n = 0; n < 4; ++n) acc[m][n] = (f32x4){0.f, 0.f, 0.f, 0.f};

#define STAGEA4(tt)                                                           \
  {                                                                           \
    char* d = smem + (((tt)&1) * 65536);                                      \
    _Pragma("unroll") for (int j = 0; j < 4; ++j)                             \
        load16(Ag + (size_t)srow[j] * K + ((tt) << 6) + skhw[j], d + sdst[j]);\
  }
#define STAGEB4(tt)                                                           \
  {                                                                           \
    char* d = smem + (((tt)&1) * 65536) + 32768;                              \
    _Pragma("unroll") for (int j = 0; j < 4; ++j)                             \
        load16(Bg + (size_t)srow[j] * K + ((tt) << 6) + skhw[j], d + sdst[j]);\
  }

  STAGEB4(0);
  STAGEA4(0);

  const int NT = K >> 6;
  const int rx = (lr & 7) << 4;
  const int aRow0 = (wr * 128 + lr) * 128;
  const int bRow0 = (wc * 64 + lr) * 128;
  const int col0 = (lg * 16) ^ rx;
  const int col1 = (64 + lg * 16) ^ rx;

  bf16x8 aR[4][2], bR[4][2];

  for (int t = 0; t < NT; ++t) {
    const char* bufA = smem + (t & 1) * 65536;
    const char* bufB = bufA + 32768;
    const bool more = (t + 1) < NT;

    asm volatile("s_waitcnt vmcnt(0)" ::: "memory");
    __builtin_amdgcn_s_barrier();

    // ---- ph0 ----
#pragma unroll
    for (int mf = 0; mf < 4; ++mf) {
      aR[mf][0] = *(const bf16x8*)(bufA + aRow0 + mf * 2048 + col0);
      aR[mf][1] = *(const bf16x8*)(bufA + aRow0 + mf * 2048 + col1);
    }
#pragma unroll
    for (int nf = 0; nf < 2; ++nf) {
      bR[nf][0] = *(const bf16x8*)(bufB + bRow0 + nf * 2048 + col0);
      bR[nf][1] = *(const bf16x8*)(bufB + bRow0 + nf * 2048 + col1);
    }
    if (more) STAGEB4(t + 1);
    asm volatile("s_waitcnt lgkmcnt(8)" ::: "memory");
    __builtin_amdgcn_s_barrier();
    asm volatile("s_waitcnt lgkmcnt(0)" ::: "memory");
    __builtin_amdgcn_sched_barrier(0);
    __builtin_amdgcn_s_setprio(1);
#pragma unroll
    for (int mf = 0; mf < 4; ++mf)
#pragma unroll
      for (int nf = 0; nf < 2; ++nf) {
        acc[mf][nf] = mfma16(aR[mf][0], bR[nf][0], acc[mf][nf]);
        acc[mf][nf] = mfma16(aR[mf][1], bR[nf][1], acc[mf][nf]);
      }
    __builtin_amdgcn_s_setprio(0);
    __builtin_amdgcn_s_barrier();

    // ---- ph1 ----
#pragma unroll
    for (int nf = 2; nf < 4; ++nf) {
      bR[nf][0] = *(const bf16x8*)(bufB + bRow0 + nf * 2048 + col0);
      bR[nf][1] = *(const bf16x8*)(bufB + bRow0 + nf * 2048 + col1);
    }
    if (more) STAGEA4(t + 1);
    __builtin_amdgcn_s_barrier();
    asm volatile("s_waitcnt lgkmcnt(0)" ::: "memory");
    __builtin_amdgcn_sched_barrier(0);
    __builtin_amdgcn_s_setprio(1);
#pragma unroll
    for (int mf = 0; mf < 4; ++mf)
#pragma unroll
      for (int nf = 2; nf < 4; ++nf) {
        acc[mf][nf] = mfma16(aR[mf][0], bR[nf][0], acc[mf][nf]);
        acc[mf][nf] = mfma16(aR[mf][1], bR[nf][1], acc[mf][nf]);
      }
    __builtin_amdgcn_s_setprio(0);
    __builtin_amdgcn_s_barrier();

    // ---- ph2 ----
#pragma unroll
    for (int mf = 0; mf < 4; ++mf) {
      aR[mf][0] = *(const bf16x8*)(bufA + aRow0 + (4 + mf) * 2048 + col0);
      aR[mf][1] = *(const bf16x8*)(bufA + aRow0 + (4 + mf) * 2048 + col1);
    }
    __builtin_amdgcn_s_barrier();
    asm volatile("s_waitcnt lgkmcnt(0)" ::: "memory");
    __builtin_amdgcn_sched_barrier(0);
    __builtin_amdgcn_s_setprio(1);
#pragma unroll
    for (int mf = 0; mf < 4; ++mf)
#pragma unroll
      for (int nf = 0; nf < 2; ++nf) {
        acc[4 + mf][nf] = mfma16(aR[mf][0], bR[nf][0], acc[4 + mf][nf]);
        acc[4 + mf][nf] = mfma16(aR[mf][1], bR[nf][1], acc[4 + mf][nf]);
      }
    __builtin_amdgcn_s_setprio(0);
    __builtin_amdgcn_s_barrier();

    // ---- ph3 ----
    __builtin_amdgcn_s_setprio(1);
#pragma unroll
    for (int mf = 0; mf < 4; ++mf)
#pragma unroll
      for (int nf = 2; nf < 4; ++nf) {
        acc[4 + mf][nf] = mfma16(aR[mf][0], bR[nf][0], acc[4 + mf][nf]);
        acc[4 + mf][nf] = mfma16(aR[mf][1], bR[nf][1], acc[4 + mf][nf]);
      }
    __builtin_amdgcn_s_setprio(0);
  }
#undef STAGEA4
#undef STAGEB4

  const float cscale = (bn < sbl) ? QSCALE : 1.0f;
#pragma unroll
  for (int mf = 0; mf < 8; ++mf)
#pragma unroll
    for (int nf = 0; nf < 4; ++nf)
#pragma unroll
      for (int r = 0; r < 4; ++r) {
        int rowc = bm * 256 + wr * 128 + mf * 16 + lg * 4 + r;
        int colc = bn * 256 + wc * 64 + nf * 16 + lr;
        float v = acc[mf][nf][r] * cscale;
        if constexpr (sizeof(OutT) == 2)
          C[(size_t)rowc * N + colc] = (OutT)f2b(v);
        else
          C[(size_t)rowc * N + colc] = v;
      }
}

// ---------------------------------------------------------------------------
// RoPE on K and V read from fused XQKV (row stride 6144; K at col 4096+,
// V at col 5120+). K -> Kr (b,kv,s,d); V -> Vt (b,kv,d,s) transposed.
__global__ __launch_bounds__(256) void rope_kv(
    const unsigned short* __restrict__ XQKV,
    const float* __restrict__ fc, const float* __restrict__ fs,
    unsigned short* __restrict__ Kr, unsigned short* __restrict__ Vt) {
  __shared__ unsigned short Vl[128][66];
  const int t = threadIdx.x;
  const int bid = blockIdx.x;  // bkv*32 + stile
  const int stile = bid & 31, bkv = bid >> 5;
  const int b = bkv >> 3, kvh = bkv & 7;
  const int s0 = stile * 64;
  const int l = t & 63;
  const int jrow = t >> 6;

  for (int j = 0; j < 16; ++j) {
    int s = s0 + j * 4 + jrow;
    ushort2 v = *(const ushort2*)(XQKV + (size_t)(b * 2048 + s) * 6144 + 4096 +
                                  kvh * 128 + 2 * l);
    float c = fc[s * 64 + l], sn = fs[s * 64 + l];
    float xr = b2f(v.x), xi = b2f(v.y);
    ushort2 o;
    o.x = f2b(xr * c - xi * sn);
    o.y = f2b(xr * sn + xi * c);
    *(ushort2*)(Kr + ((size_t)bkv * 2048 + s) * 128 + 2 * l) = o;
  }
  for (int j = 0; j < 16; ++j) {
    int ss = j * 4 + jrow;
    int s = s0 + ss;
    ushort2 v = *(const ushort2*)(XQKV + (size_t)(b * 2048 + s) * 6144 + 5120 +
                                  kvh * 128 + 2 * l);
    float c = fc[s * 64 + l], sn = fs[s * 64 + l];
    float xr = b2f(v.x), xi = b2f(v.y);
    Vl[2 * l][ss] = f2b(xr * c - xi * sn);
    Vl[2 * l + 1][ss] = f2b(xr * sn + xi * c);
  }
  __syncthreads();
  const int d = t >> 1, half = t & 1;
  unsigned short* vdst = Vt + ((size_t)bkv * 128 + d) * 2048 + s0 + half * 32;
#pragma unroll
  for (int e = 0; e < 32; e += 4) {
    ushort4 pk;
    pk.x = Vl[d][half * 32 + e];
    pk.y = Vl[d][half * 32 + e + 1];
    pk.z = Vl[d][half * 32 + e + 2];
    pk.w = Vl[d][half * 32 + e + 3];
    *(ushort4*)(vdst + e) = pk;
  }
}

// ---------------------------------------------------------------------------
// Flash attention (round-6 structure; XQ row stride 6144; native bf16 cvt).
__global__ __launch_bounds__(256, 2) void attn_fwd(
    const unsigned short* __restrict__ XQ, const unsigned short* __restrict__ Kr,
    const unsigned short* __restrict__ Vt, unsigned short* __restrict__ AO) {
  extern __shared__ char smem[];  // 81920
  char* Ksm = smem;                                      // [2][16384]
  char* Vsm = smem + 32768;                              // [2][16384]
  unsigned short* Ps = (unsigned short*)(smem + 65536);  // [4][8][32][8]
  const int t = threadIdx.x;
  const int lane = t & 63, w = t >> 6;
  const int lr = lane & 15, lg = lane >> 4;

  const int bid = blockIdx.x;
  const int nwg = gridDim.x;  // 1024
  const int swz = (bid & 7) * (nwg >> 3) + (bid >> 3);
  const int qt = swz & 15;
  const int bh = swz >> 4;
  const int b = bh >> 5, h = bh & 31;
  const int bkv = b * 8 + (h >> 2);

  bf16x8 qf[2][4];
#pragma unroll
  for (int q2 = 0; q2 < 2; ++q2) {
    const unsigned short* qp =
        XQ + ((size_t)(b * 2048 + qt * 128 + w * 32 + q2 * 16 + lr)) * 6144 +
        h * 128 + lg * 8;
#pragma unroll
    for (int dc = 0; dc < 4; ++dc) qf[q2][dc] = *(const bf16x8*)(qp + dc * 32);
  }

  f32x4 acc[2][8];
#pragma unroll
  for (int q2 = 0; q2 < 2; ++q2)
#pragma unroll
    for (int i = 0; i < 8; ++i) acc[q2][i] = (f32x4){0.f, 0.f, 0.f, 0.f};
  float l_[2][4] = {{0.f, 0.f, 0.f, 0.f}, {0.f, 0.f, 0.f, 0.f}};

  const unsigned short* Kbase = Kr + (size_t)bkv * 2048 * 128;
  const unsigned short* Vbase = Vt + (size_t)bkv * 128 * 2048;

  int kK[4], dC[4], vD[4], vKc[4], dstb[4];
#pragma unroll
  for (int j = 0; j < 4; ++j) {
    const int c = t + j * 256;
    kK[j] = c & 63;  dC[j] = c >> 6;
    vD[j] = c & 127; vKc[j] = c >> 7;
    dstb[j] = (c & ~63) * 16;
  }

#define STAGE_KV(bufi, kt)                                                    \
  {                                                                           \
    char* kd = Ksm + (bufi)*16384;                                            \
    char* vd = Vsm + (bufi)*16384;                                            \
    _Pragma("unroll") for (int j = 0; j < 4; ++j) {                           \
      load16(Kbase + (size_t)((kt)*64 + kK[j]) * 128 + dC[j] * 8, kd + dstb[j]); \
      load16(Vbase + (size_t)vD[j] * 2048 + (kt)*64 + vKc[j] * 8, vd + dstb[j]); \
    }                                                                         \
  }

  STAGE_KV(0, 0);
  asm volatile("s_waitcnt vmcnt(0)" ::: "memory");
  __builtin_amdgcn_s_barrier();

  unsigned short* Pw = Ps + w * 2048;              // [8 kc][32 q][8]
  const int pbase = (lr >> 3) * 256 + (lr & 7);    // halfword offset

  for (int kt = 0; kt < 32; ++kt) {
    const int cur = kt & 1;
    if (kt < 31) STAGE_KV(cur ^ 1, kt + 1);

    const char* Kc = Ksm + cur * 16384;
    const char* Vc = Vsm + cur * 16384;

#pragma unroll
    for (int nf = 0; nf < 4; ++nf) {
      f32x4 s0 = (f32x4){0.f, 0.f, 0.f, 0.f};
      f32x4 s1 = (f32x4){0.f, 0.f, 0.f, 0.f};
#pragma unroll
      for (int dc = 0; dc < 4; ++dc) {
        bf16x8 kf =
            *(const bf16x8*)(Kc + ((dc * 4 + lg) * 64 + nf * 16 + lr) * 16);
        s0 = mfma16(qf[0][dc], kf, s0);
        s1 = mfma16(qf[1][dc], kf, s1);
      }
      const int pb = pbase + nf * 512;  // kc = nf*2 + (lr>>3)
#pragma unroll
      for (int r = 0; r < 4; ++r) {
        float p0 = __builtin_amdgcn_exp2f(s0[r]);
        float p1 = __builtin_amdgcn_exp2f(s1[r]);
        l_[0][r] += p0;
        l_[1][r] += p1;
        Pw[pb + (lg * 4 + r) * 8] = f2b_fast(p0);
        Pw[pb + (16 + lg * 4 + r) * 8] = f2b_fast(p1);
      }
    }

#pragma unroll
    for (int ks = 0; ks < 2; ++ks) {
      bf16x8 pf0 = *(const bf16x8*)(Pw + (ks * 4 + lg) * 256 + lr * 8);
      bf16x8 pf1 = *(const bf16x8*)(Pw + (ks * 4 + lg) * 256 + (16 + lr) * 8);
#pragma unroll
      for (int dt = 0; dt < 8; ++dt) {
        bf16x8 vf =
            *(const bf16x8*)(Vc + ((ks * 4 + lg) * 128 + dt * 16 + lr) * 16);
        acc[0][dt] = mfma16(pf0, vf, acc[0][dt]);
        acc[1][dt] = mfma16(pf1, vf, acc[1][dt]);
      }
    }

    asm volatile("s_waitcnt vmcnt(0)" ::: "memory");
    __builtin_amdgcn_s_barrier();
  }
#undef STAGE_KV

#pragma unroll
  for (int q2 = 0; q2 < 2; ++q2)
#pragma unroll
    for (int r = 0; r < 4; ++r) {
#pragma unroll
      for (int o = 1; o < 16; o <<= 1) l_[q2][r] += __shfl_xor(l_[q2][r], o);
    }

#pragma unroll
  for (int q2 = 0; q2 < 2; ++q2)
#pragma unroll
    for (int r = 0; r < 4; ++r) {
      float inv = 1.f / l_[q2][r];
      size_t rowb =
          ((size_t)(b * 2048 + qt * 128 + w * 32 + q2 * 16 + lg * 4 + r)) * 4096 +
          h * 128;
#pragma unroll
      for (int dt = 0; dt < 8; ++dt)
        AO[rowb + dt * 16 + lr] = f2b_fast(acc[q2][dt][r] * inv);
    }
}

// ---------------------------------------------------------------------------
extern "C" void kernel_launch(void* const* d_in, const int* in_sizes, int n_in,
                              void* d_out, int out_size, void* d_ws, size_t ws_size,
                              hipStream_t stream) {
  const float* x  = (const float*)d_in[0];
  const float* fc = (const float*)d_in[2];
  const float* fs = (const float*)d_in[3];
  const float* wq = (const float*)d_in[4];
  const float* wk = (const float*)d_in[5];
  const float* wv = (const float*)d_in[6];
  const float* wo = (const float*)d_in[7];

  const size_t MB = 1024ull * 1024ull;
  char* ws = (char*)d_ws;
  unsigned short* Xb   = (unsigned short*)(ws);           // 32MB, dead after QKV gemm
  unsigned short* Wsc  = (unsigned short*)(ws + 32 * MB); // 48MB (wq|wk|wv), later wo
  unsigned short* Kr   = (unsigned short*)(ws);           // [0,8) reuse Xb
  unsigned short* Vt   = (unsigned short*)(ws + 8 * MB);  // [8,16)
  unsigned short* AO   = (unsigned short*)(ws + 80 * MB); // 32MB
  unsigned short* XQKV = (unsigned short*)d_out;          // 48MB of 64MB d_out

  (void)hipFuncSetAttribute((const void*)gemm256<unsigned short>,
                            hipFuncAttributeMaxDynamicSharedMemorySize, 131072);
  (void)hipFuncSetAttribute((const void*)gemm256<float>,
                            hipFuncAttributeMaxDynamicSharedMemorySize, 131072);
  (void)hipFuncSetAttribute((const void*)attn_fwd,
                            hipFuncAttributeMaxDynamicSharedMemorySize, 81920);

  dim3 blk(256);
  dim3 blk512(512);
  cvt_f32_bf16<<<2048, blk, 0, stream>>>(x, Xb, (2 * 2048 * 4096) / 4);
  cvt_f32_bf16<<<2048, blk, 0, stream>>>(wq, Wsc, (4096 * 4096) / 4);
  cvt_f32_bf16<<<2048, blk, 0, stream>>>(wk, Wsc + 4096 * 4096, (1024 * 4096) / 4);
  cvt_f32_bf16<<<2048, blk, 0, stream>>>(wv, Wsc + 5120 * 4096, (1024 * 4096) / 4);
  gemm256<unsigned short><<<384, blk512, 131072, stream>>>(
      Xb, Wsc, XQKV, 4096, 6144, 4096, /*sbl=*/16);
  rope_kv<<<512, blk, 0, stream>>>(XQKV, fc, fs, Kr, Vt);
  attn_fwd<<<1024, blk, 81920, stream>>>(XQKV, Kr, Vt, AO);
  cvt_f32_bf16<<<2048, blk, 0, stream>>>(wo, Wsc, (4096 * 4096) / 4);
  gemm256<float><<<256, blk512, 131072, stream>>>(
      AO, Wsc, (float*)d_out, 4096, 4096, 4096, /*sbl=*/0);
}